// Round 15
// baseline (184.192 us; speedup 1.0000x reference)
//
#include <hip/hip_runtime.h>
#include <hip/hip_bf16.h>

#define Bb 2
#define Tt 2048
#define Cc 1024
#define Hh 16
#define Dd 64

typedef __bf16 bf8 __attribute__((ext_vector_type(8)));
typedef __bf16 bf4 __attribute__((ext_vector_type(4)));
typedef float f4 __attribute__((ext_vector_type(4)));

typedef __attribute__((address_space(3))) void lds_void;
typedef const __attribute__((address_space(1))) void g_void;

__device__ __forceinline__ void gload_lds16(const __bf16* g, __bf16* l) {
  __builtin_amdgcn_global_load_lds((g_void*)g, (lds_void*)l, 16, 0, 0);
}

// exp2 that lowers directly to v_exp_f32 (hw exp is base-2)
__device__ __forceinline__ float ex2(float x) { return __builtin_amdgcn_exp2f(x); }

// fused fp32 -> bf16 convert for x, W_qkv, W_proj in one launch
__global__ __launch_bounds__(256) void cvt3_kernel(
    const float* __restrict__ a, __bf16* __restrict__ oa, int na,
    const float* __restrict__ b, __bf16* __restrict__ ob, int nb,
    const float* __restrict__ c, __bf16* __restrict__ oc) {
  int gi = blockIdx.x * 256 + threadIdx.x;
  const int t0 = na >> 3, t1 = t0 + (nb >> 3);
  const float* src; __bf16* dst; int idx;
  if (gi < t0)      { src = a; dst = oa; idx = gi; }
  else if (gi < t1) { src = b; dst = ob; idx = gi - t0; }
  else              { src = c; dst = oc; idx = gi - t1; }
  const float* p = src + (size_t)idx * 8;
  float4 u = *(const float4*)p;
  float4 v = *(const float4*)(p + 4);
  bf8 r;
  r[0] = (__bf16)u.x; r[1] = (__bf16)u.y; r[2] = (__bf16)u.z; r[3] = (__bf16)u.w;
  r[4] = (__bf16)v.x; r[5] = (__bf16)v.y; r[6] = (__bf16)v.z; r[7] = (__bf16)v.w;
  *(bf8*)(dst + (size_t)idx * 8) = r;
}

// QKV GEMM, R15: 128x64 tiles -> 1536 blocks (6/CU TLP; the regime law from
// R12-proj / R13-R14-attn: TLP pays).  Double-buffered DMA staging (one
// barrier/iter).  LDS = A-dbuf 16K + B-dbuf 8K = 24 KB; v-transpose Epi
// (32x72/wave, 18 KB) unions into it after the post-loop barrier.
// Wave owns 64 rows x 32 cols: acc[4][2], 8 MFMA + 6 ds_read_b128 per iter.
// q pre-scaled 0.125*log2e; v written t-contiguous via Epi.
__global__ __launch_bounds__(256) void gemm128_kernel(
    const __bf16* __restrict__ A, const __bf16* __restrict__ W,
    const float* __restrict__ bias, int K,
    __bf16* __restrict__ q_ws, __bf16* __restrict__ k_ws,
    __bf16* __restrict__ v_ws)
{
  const int tid = threadIdx.x;
  const int lane = tid & 63, wave = tid >> 6;
  const int lr = lane & 15, lq = lane >> 4;
  const int m_blk = blockIdx.y * 128, n_blk = blockIdx.x * 64;
  const int wm = (wave & 1) * 64, wn = (wave >> 1) * 32;

  // union: As0[0,4096) As1[4096,8192) Bs0[8192,10240) Bs1[10240,12288) elems
  // (24 KB); Epi overlays as 4 x (32*72) after the post-loop barrier (18 KB).
  __shared__ __align__(16) __bf16 smem[12288];

  const int srow = tid >> 2, scol = (tid & 3) * 8;
  const __bf16* ag0 = A + (size_t)(m_blk + srow) * K + scol;        // A rows 0..63
  const __bf16* ag1 = ag0 + (size_t)64 * K;                         // A rows 64..127
  const __bf16* bg  = W + (size_t)(n_blk + srow) * K + scol;        // B rows 0..63

  auto stage = [&](int k0, int bsel) {
    __bf16* as = smem + bsel * 4096;
    __bf16* bs = smem + 8192 + bsel * 2048;
    gload_lds16(ag0 + k0, as + tid * 8);
    gload_lds16(ag1 + k0, as + 2048 + tid * 8);
    gload_lds16(bg + k0, bs + tid * 8);
  };

  f4 acc[4][2] = {};
  const int nk = K >> 5;

  stage(0, 0);
  for (int k = 0; k < nk; ++k) {
    __syncthreads();   // drains DMA(k); all waves done reading buf[k&1] (iter k-2)
    if (k + 1 < nk) stage((k + 1) * 32, (k + 1) & 1);

    const __bf16* As = smem + (k & 1) * 4096;
    const __bf16* Bs = smem + 8192 + (k & 1) * 2048;
    bf8 af[4], bfr[2];
    #pragma unroll
    for (int i = 0; i < 4; ++i)
      af[i] = *(const bf8*)&As[(wm + i * 16 + lr) * 32 + lq * 8];
    #pragma unroll
    for (int j = 0; j < 2; ++j)
      bfr[j] = *(const bf8*)&Bs[(wn + j * 16 + lr) * 32 + lq * 8];
    #pragma unroll
    for (int i = 0; i < 4; ++i)
      #pragma unroll
      for (int j = 0; j < 2; ++j)
        acc[i][j] = __builtin_amdgcn_mfma_f32_16x16x32_bf16(af[i], bfr[j], acc[i][j], 0, 0, 0);
  }
  __syncthreads();   // staging dead; Epi may overlay it

  const int col0 = n_blk + wn;          // 32-aligned -> which/h wave-uniform
  const int which = col0 >> 10;
  const int b = m_blk >> 11;            // 128-row blocks never straddle b
  const int h = (col0 & 1023) >> 6;
  const size_t bh = (size_t)b * Hh + h;

  if (which == 2) {
    // v: transpose through per-wave LDS (32 d-cols x 64 t-rows), write t-contig
    __bf16* E = smem + wave * 2304;     // 32*72 per wave
    #pragma unroll
    for (int j = 0; j < 2; ++j) {
      float bv = bias[col0 + j * 16 + lr];
      #pragma unroll
      for (int i = 0; i < 4; ++i)
        #pragma unroll
        for (int r = 0; r < 4; ++r)
          E[(j * 16 + lr) * 72 + i * 16 + lq * 4 + r] = (__bf16)(acc[i][j][r] + bv);
    }
    asm volatile("s_waitcnt lgkmcnt(0)" ::: "memory");  // wave-private RAW
    const int t0 = (m_blk + wm) & 2047;
    const int d_base = col0 & 63;
    const int dd = lane >> 3, tl = (lane & 7) * 8;
    #pragma unroll
    for (int di = 0; di < 4; ++di) {
      int dl = di * 8 + dd;            // 0..31 within the wave's 32 d-cols
      bf8 vv = *(const bf8*)&E[dl * 72 + tl];
      *(bf8*)&v_ws[(bh * Dd + d_base + dl) * Tt + t0 + tl] = vv;
    }
  } else {
    __bf16* dst = (which == 0) ? q_ws : k_ws;
    const float scl = (which == 0) ? 0.18033688011112042f : 1.0f;  // 1/sqrt(D)*log2e
    #pragma unroll
    for (int i = 0; i < 4; ++i) {
      #pragma unroll
      for (int j = 0; j < 2; ++j) {
        #pragma unroll
        for (int r = 0; r < 4; ++r) {
          int row = m_blk + wm + i * 16 + lq * 4 + r;  // C/D: row = 4*quad + reg
          int col = col0 + j * 16 + lr;                // C/D: col = lane&15
          float val = (acc[i][j][r] + bias[col]) * scl;
          int d = col & 63, t = row & 2047;
          dst[(bh * Tt + t) * Dd + d] = (__bf16)val;
        }
      }
    }
  }
}

// Proj GEMM: 64x64 tiles -> 1024 blocks (4/CU TLP).  8 KB LDS, single-buffer.
__global__ __launch_bounds__(256) void gemm64_kernel(
    const __bf16* __restrict__ A, const __bf16* __restrict__ W,
    const float* __restrict__ bias, int K, float* __restrict__ out, int ldo)
{
  const int tid = threadIdx.x;
  const int lane = tid & 63, wave = tid >> 6;
  const int lr = lane & 15, lq = lane >> 4;
  const int m_blk = blockIdx.y * 64, n_blk = blockIdx.x * 64;
  const int wm = (wave & 1) * 32, wn = (wave >> 1) * 32;

  __shared__ __align__(16) __bf16 As[64 * 32];
  __shared__ __align__(16) __bf16 Bs[64 * 32];

  const int srow = tid >> 2, scol = (tid & 3) * 8;
  const __bf16* ag = A + (size_t)(m_blk + srow) * K + scol;
  const __bf16* bg = W + (size_t)(n_blk + srow) * K + scol;
  __bf16* al = As + tid * 8;
  __bf16* bl = Bs + tid * 8;

  f4 acc[2][2] = {};
  for (int k0 = 0; k0 < K; k0 += 32) {
    gload_lds16(ag + k0, al);
    gload_lds16(bg + k0, bl);
    __syncthreads();

    bf8 af[2], bfr[2];
    #pragma unroll
    for (int i = 0; i < 2; ++i)
      af[i] = *(const bf8*)&As[(wm + i * 16 + lr) * 32 + lq * 8];
    #pragma unroll
    for (int j = 0; j < 2; ++j)
      bfr[j] = *(const bf8*)&Bs[(wn + j * 16 + lr) * 32 + lq * 8];
    #pragma unroll
    for (int i = 0; i < 2; ++i)
      #pragma unroll
      for (int j = 0; j < 2; ++j)
        acc[i][j] = __builtin_amdgcn_mfma_f32_16x16x32_bf16(af[i], bfr[j], acc[i][j], 0, 0, 0);
    __syncthreads();
  }

  #pragma unroll
  for (int i = 0; i < 2; ++i)
    #pragma unroll
    for (int j = 0; j < 2; ++j)
      #pragma unroll
      for (int r = 0; r < 4; ++r) {
        int row = m_blk + wm + i * 16 + lq * 4 + r;
        int col = n_blk + wn + j * 16 + lr;
        out[(size_t)row * ldo + col] = acc[i][j][r] + bias[col];
      }
}

// Flash attention with sink, fixed softmax reference m=0, log2-domain scores.
// 1024 blocks x 256 threads (4 waves x 16 q = 64 q/block), K/V double-
// buffered (40 KB LDS -> 4 blocks/CU).  Balanced pairing: qt + qt' = 31.
__global__ __launch_bounds__(256) void attn_kernel(
    const __bf16* __restrict__ q_ws, const __bf16* __restrict__ k_ws,
    const __bf16* __restrict__ v_ws, const float* __restrict__ sink,
    __bf16* __restrict__ y_ws)
{
  int bi = blockIdx.x;
  int qt, bhi;
  if (bi < 512) { qt = 31 - (bi >> 5); bhi = bi & 31; }
  else          { qt = (bi - 512) >> 5; bhi = (bi - 512) & 31; }
  const int h = bhi & (Hh - 1);
  const int b = bhi >> 4;
  const int tid = threadIdx.x;
  const int lane = tid & 63, wave = tid >> 6;          // wave 0..3
  const int lr = lane & 15, lq = lane >> 4;

  __shared__ __align__(16) __bf16 KsU[2][64 * 64];     // swizzled [key][d], dbuf
  __shared__ __align__(16) __bf16 VtU[2][64 * 64];     // swizzled [d][key], dbuf
  __shared__ __align__(16) __bf16 PsU[4][16 * 64];     // per-wave [q][key]

  const __bf16* qp = q_ws + (size_t)bhi * Tt * Dd;
  const __bf16* kp = k_ws + (size_t)bhi * Tt * Dd;
  const __bf16* vp = v_ws + (size_t)bhi * Dd * Tt;     // [d][t]

  const int qbase = qt * 64;
  const int qlo = qbase + wave * 16;                   // wave's lowest q row

  // Q fragments: 16 rows/wave, loop-invariant registers
  bf8 qf[2];
  {
    const __bf16* qrow = qp + (size_t)(qlo + lr) * Dd;
    qf[0] = *(const bf8*)(qrow + lq * 8);
    qf[1] = *(const bf8*)(qrow + 32 + lq * 8);
  }

  float rs = 0.f;             // per-lane denominator partial (q = lr)
  f4 o_acc[4] = {};

  // staging: 256 threads, 2 K chunks + 2 V chunks each (64 rows x 8 slots)
  const int srow_lo = tid >> 3;         // 0..31
  const int sslot = tid & 7;
  const int nkt = qt + 1;

  auto stage = [&](int kt2, int bsel) {
    const int kbase2 = kt2 * 64;
    #pragma unroll
    for (int ii = 0; ii < 2; ++ii) {
      const int r = ii * 32 + srow_lo;
      const int cc = sslot ^ (r & 7);            // XOR granule swizzle
      gload_lds16(kp + (size_t)(kbase2 + r) * Dd + cc * 8,
                  &KsU[bsel][ii * 2048 + tid * 8]);
      gload_lds16(vp + (size_t)r * Tt + kbase2 + cc * 8,
                  &VtU[bsel][ii * 2048 + tid * 8]);
    }
  };

  stage(0, 0);
  for (int kt = 0; kt < nkt; ++kt) {
    __syncthreads();        // drains DMA(kt); readers of buf[kt&1] (iter kt-2) done
    if (kt + 1 < nkt) stage(kt + 1, (kt + 1) & 1);

    const __bf16* Kb = KsU[kt & 1];
    const __bf16* Vb = VtU[kt & 1];
    const int kbase = kt * 64;

    // S^T = K Q^T (A=K rows, B=Q rows): c[r] = S[key=kbase+nt*16+lq*4+r][q=qlo+lr]
    f4 s[4];
    #pragma unroll
    for (int nt = 0; nt < 4; ++nt) {
      const int krow = nt * 16 + lr;
      const int x7 = krow & 7;
      bf8 kb0 = *(const bf8*)&Kb[krow * 64 + ((lq ^ x7) * 8)];
      bf8 kb1 = *(const bf8*)&Kb[krow * 64 + (((4 + lq) ^ x7) * 8)];
      f4 c = {};
      c = __builtin_amdgcn_mfma_f32_16x16x32_bf16(kb0, qf[0], c, 0, 0, 0);
      c = __builtin_amdgcn_mfma_f32_16x16x32_bf16(kb1, qf[1], c, 0, 0, 0);
      s[nt] = c;
    }

    __bf16* Pw = PsU[wave];
    if (kt == qt) {         // diagonal tile (only one per wave at 64-q blocks)
      #pragma unroll
      for (int nt = 0; nt < 4; ++nt) {
        const int qg = qlo + lr;
        const int kg = kbase + nt * 16 + lq * 4;
        bf4 pb;
        #pragma unroll
        for (int r = 0; r < 4; ++r) {
          float sv = (kg + r > qg) ? -1e30f : s[nt][r];
          float p = ex2(sv);              // scores already in log2 domain
          rs += p;
          pb[r] = (__bf16)p;
        }
        const int G = (nt * 2 + (lq >> 1)) ^ (lr & 7);
        *(bf4*)&Pw[lr * 64 + G * 8 + (lq & 1) * 4] = pb;
      }
    } else {
      #pragma unroll
      for (int nt = 0; nt < 4; ++nt) {
        bf4 pb;
        #pragma unroll
        for (int r = 0; r < 4; ++r) {
          float p = ex2(s[nt][r]);
          rs += p;
          pb[r] = (__bf16)p;
        }
        const int G = (nt * 2 + (lq >> 1)) ^ (lr & 7);
        *(bf4*)&Pw[lr * 64 + G * 8 + (lq & 1) * 4] = pb;
      }
    }
    asm volatile("s_waitcnt lgkmcnt(0)" ::: "memory");  // wave-private RAW on Pw

    // O += P @ V
    #pragma unroll
    for (int ks = 0; ks < 2; ++ks) {
      const int pg = ((ks * 4 + lq) ^ (lr & 7)) * 8;
      bf8 pa = *(const bf8*)&Pw[lr * 64 + pg];
      #pragma unroll
      for (int dt = 0; dt < 4; ++dt) {
        const int vrow = dt * 16 + lr;
        bf8 vb = *(const bf8*)&Vb[vrow * 64 + (((ks * 4 + lq) ^ (vrow & 7)) * 8)];
        o_acc[dt] = __builtin_amdgcn_mfma_f32_16x16x32_bf16(pa, vb, o_acc[dt], 0, 0, 0);
      }
    }
  }

  // denominator: reduce per-lane partials over lq (lanes sharing lr)
  rs += __shfl_xor(rs, 16, 64);
  rs += __shfl_xor(rs, 32, 64);
  const float snk = ex2(sink[h] * 1.44269504f);   // e^sink
  float inv = 1.0f / (rs + snk);
  // redistribute: O rows are q = lq*4+r; denom lives at lane with lr == lq*4+r
  float invr[4];
  #pragma unroll
  for (int r = 0; r < 4; ++r)
    invr[r] = __shfl(inv, lq * 4 + r, 64);

  #pragma unroll
  for (int dt = 0; dt < 4; ++dt)
    #pragma unroll
    for (int r = 0; r < 4; ++r) {
      int qrow = qlo + lq * 4 + r;
      y_ws[((size_t)b * Tt + qrow) * Cc + h * Dd + dt * 16 + lr] =
          (__bf16)(o_acc[dt][r] * invr[r]);
    }
}

extern "C" void kernel_launch(void* const* d_in, const int* in_sizes, int n_in,
                              void* d_out, int out_size, void* d_ws, size_t ws_size,
                              hipStream_t stream) {
  const float* x      = (const float*)d_in[0];
  const float* W_qkv  = (const float*)d_in[1];
  const float* b_qkv  = (const float*)d_in[2];
  const float* W_proj = (const float*)d_in[3];
  const float* b_proj = (const float*)d_in[4];
  const float* sinkp  = (const float*)d_in[5];
  float* out = (float*)d_out;

  const size_t n_x    = (size_t)Bb * Tt * Cc;        // 4.19M
  const size_t n_wqkv = (size_t)3 * Hh * Dd * Cc;    // 3.15M
  const size_t n_wprj = (size_t)Cc * Hh * Dd;        // 1.05M
  const size_t nqkv   = (size_t)Bb * Hh * Tt * Dd;   // 4.19M

  __bf16* xb     = (__bf16*)d_ws;          // also aliased as y_ws after QKV GEMM
  __bf16* wqkvb  = xb + n_x;
  __bf16* wprojb = wqkvb + n_wqkv;
  __bf16* q_ws   = wprojb + n_wprj;
  __bf16* k_ws   = q_ws + nqkv;
  __bf16* v_ws   = k_ws + nqkv;
  __bf16* y_ws   = xb;                     // lifetime-disjoint alias

  dim3 blk(256);
  const int cvt_blocks = (int)((n_x + n_wqkv + n_wprj) / 8 / 256);  // 4096
  cvt3_kernel<<<cvt_blocks, blk, 0, stream>>>(x, xb, (int)n_x,
                                              W_qkv, wqkvb, (int)n_wqkv,
                                              W_proj, wprojb);

  // QKV: M=4096, N=3072, K=1024 — 128x64 tiles -> 1536 blocks (6/CU), dbuf
  gemm128_kernel<<<dim3(3 * Cc / 64, Bb * Tt / 128), blk, 0, stream>>>(
      xb, wqkvb, b_qkv, Cc, q_ws, k_ws, v_ws);
  // attention: 1024 balanced-pair blocks, 256 threads, 4 blocks/CU
  attn_kernel<<<dim3(1024), blk, 0, stream>>>(q_ws, k_ws, v_ws, sinkp, y_ws);
  // proj: M=4096, N=1024, K=1024 — 64x64 tiles -> 1024 blocks (4/CU)
  gemm64_kernel<<<dim3(Cc / 64, Bb * Tt / 64), blk, 0, stream>>>(
      y_ws, wprojb, b_proj, Hh * Dd, out, Cc);
}

// Round 16
// 169.925 us; speedup vs baseline: 1.0840x; 1.0840x over previous
//
#include <hip/hip_runtime.h>
#include <hip/hip_bf16.h>

#define Bb 2
#define Tt 2048
#define Cc 1024
#define Hh 16
#define Dd 64

typedef __bf16 bf8 __attribute__((ext_vector_type(8)));
typedef __bf16 bf4 __attribute__((ext_vector_type(4)));
typedef float f4 __attribute__((ext_vector_type(4)));

typedef __attribute__((address_space(3))) void lds_void;
typedef const __attribute__((address_space(1))) void g_void;

__device__ __forceinline__ void gload_lds16(const __bf16* g, __bf16* l) {
  __builtin_amdgcn_global_load_lds((g_void*)g, (lds_void*)l, 16, 0, 0);
}

// exp2 that lowers directly to v_exp_f32 (hw exp is base-2)
__device__ __forceinline__ float ex2(float x) { return __builtin_amdgcn_exp2f(x); }

// fused fp32 -> bf16 convert for x, W_qkv, W_proj in one launch
__global__ __launch_bounds__(256) void cvt3_kernel(
    const float* __restrict__ a, __bf16* __restrict__ oa, int na,
    const float* __restrict__ b, __bf16* __restrict__ ob, int nb,
    const float* __restrict__ c, __bf16* __restrict__ oc) {
  int gi = blockIdx.x * 256 + threadIdx.x;
  const int t0 = na >> 3, t1 = t0 + (nb >> 3);
  const float* src; __bf16* dst; int idx;
  if (gi < t0)      { src = a; dst = oa; idx = gi; }
  else if (gi < t1) { src = b; dst = ob; idx = gi - t0; }
  else              { src = c; dst = oc; idx = gi - t1; }
  const float* p = src + (size_t)idx * 8;
  float4 u = *(const float4*)p;
  float4 v = *(const float4*)(p + 4);
  bf8 r;
  r[0] = (__bf16)u.x; r[1] = (__bf16)u.y; r[2] = (__bf16)u.z; r[3] = (__bf16)u.w;
  r[4] = (__bf16)v.x; r[5] = (__bf16)v.y; r[6] = (__bf16)v.z; r[7] = (__bf16)v.w;
  *(bf8*)(dst + (size_t)idx * 8) = r;
}

// QKV GEMM (R14 config — best measured): 128x128 tile, BK=32, 16x16x32 MFMA,
// DOUBLE-BUFFERED DMA staging (one barrier/iter).  Epi v-transpose buffer
// unions with staging (post-loop barrier) -> LDS 36 KB, 3 blocks/CU.
// R15's 128x64/6-CU variant regressed (TLP saturates at ~4 blocks/CU; B
// staged 2x, conflicts up) — do not shrink tiles further.
// q pre-scaled 0.125*log2e; v written t-contiguous via Epi.
__global__ __launch_bounds__(256) void gemm128_kernel(
    const __bf16* __restrict__ A, const __bf16* __restrict__ W,
    const float* __restrict__ bias, int K,
    __bf16* __restrict__ q_ws, __bf16* __restrict__ k_ws,
    __bf16* __restrict__ v_ws)
{
  const int tid = threadIdx.x;
  const int lane = tid & 63, wave = tid >> 6;
  const int lr = lane & 15, lq = lane >> 4;
  const int m_blk = blockIdx.y * 128, n_blk = blockIdx.x * 128;
  const int wm = (wave & 1) * 64, wn = (wave >> 1) * 64;

  // union: [ As0 4K | As1 4K | Bs0 4K | Bs1 4K ] elems (32 KB) overlaid by
  // Epi[4][64*72] (36 KB) after the post-loop barrier.
  __shared__ __align__(16) __bf16 smem[4 * 64 * 72];
  __bf16* AsB = smem;             // AsB + bsel*4096
  __bf16* BsB = smem + 8192;      // BsB + bsel*4096

  const int srow = tid >> 2, scol = (tid & 3) * 8;
  const __bf16* ag0 = A + (size_t)(m_blk + srow) * K + scol;
  const __bf16* ag1 = A + (size_t)(m_blk + 64 + srow) * K + scol;
  const __bf16* bg0 = W + (size_t)(n_blk + srow) * K + scol;
  const __bf16* bg1 = W + (size_t)(n_blk + 64 + srow) * K + scol;

  auto stage = [&](int k0, int bsel) {
    __bf16* as = AsB + bsel * 4096;
    __bf16* bs = BsB + bsel * 4096;
    gload_lds16(ag0 + k0, as + tid * 8);
    gload_lds16(ag1 + k0, as + 2048 + tid * 8);
    gload_lds16(bg0 + k0, bs + tid * 8);
    gload_lds16(bg1 + k0, bs + 2048 + tid * 8);
  };

  f4 acc[4][4] = {};
  const int nk = K >> 5;

  stage(0, 0);
  for (int k = 0; k < nk; ++k) {
    __syncthreads();   // drains DMA(k); all waves done reading buf[k&1] (iter k-2)
    if (k + 1 < nk) stage((k + 1) * 32, (k + 1) & 1);

    const __bf16* As = AsB + (k & 1) * 4096;
    const __bf16* Bs = BsB + (k & 1) * 4096;
    bf8 af[4], bfr[4];
    #pragma unroll
    for (int i = 0; i < 4; ++i)
      af[i] = *(const bf8*)&As[(wm + i * 16 + lr) * 32 + lq * 8];
    #pragma unroll
    for (int j = 0; j < 4; ++j)
      bfr[j] = *(const bf8*)&Bs[(wn + j * 16 + lr) * 32 + lq * 8];
    #pragma unroll
    for (int i = 0; i < 4; ++i)
      #pragma unroll
      for (int j = 0; j < 4; ++j)
        acc[i][j] = __builtin_amdgcn_mfma_f32_16x16x32_bf16(af[i], bfr[j], acc[i][j], 0, 0, 0);
  }
  __syncthreads();   // staging dead; Epi may overlay it

  const int col0 = n_blk + wn;          // 64-aligned -> which/h wave-uniform
  const int which = col0 >> 10;
  const int b = m_blk >> 11;            // 128-row blocks never straddle b
  const int h = (col0 & 1023) >> 6;
  const size_t bh = (size_t)b * Hh + h;

  if (which == 2) {
    // v: transpose through per-wave LDS, write t-contiguous
    __bf16* E = smem + wave * 4608;     // 64*72 per wave
    #pragma unroll
    for (int j = 0; j < 4; ++j) {
      float bv = bias[col0 + j * 16 + lr];
      #pragma unroll
      for (int i = 0; i < 4; ++i)
        #pragma unroll
        for (int r = 0; r < 4; ++r)
          E[(j * 16 + lr) * 72 + i * 16 + lq * 4 + r] = (__bf16)(acc[i][j][r] + bv);
    }
    asm volatile("s_waitcnt lgkmcnt(0)" ::: "memory");  // wave-private RAW
    const int t0 = (m_blk + wm) & 2047;
    const int dd = lane >> 3, tl = (lane & 7) * 8;
    #pragma unroll
    for (int di = 0; di < 8; ++di) {
      int d = di * 8 + dd;
      bf8 vv = *(const bf8*)&E[d * 72 + tl];
      *(bf8*)&v_ws[(bh * Dd + d) * Tt + t0 + tl] = vv;
    }
  } else {
    __bf16* dst = (which == 0) ? q_ws : k_ws;
    const float scl = (which == 0) ? 0.18033688011112042f : 1.0f;  // 1/sqrt(D)*log2e
    #pragma unroll
    for (int i = 0; i < 4; ++i) {
      #pragma unroll
      for (int j = 0; j < 4; ++j) {
        #pragma unroll
        for (int r = 0; r < 4; ++r) {
          int row = m_blk + wm + i * 16 + lq * 4 + r;  // C/D: row = 4*quad + reg
          int col = col0 + j * 16 + lr;                // C/D: col = lane&15
          float val = (acc[i][j][r] + bias[col]) * scl;
          int d = col & 63, t = row & 2047;
          dst[(bh * Tt + t) * Dd + d] = (__bf16)val;
        }
      }
    }
  }
}

// Proj GEMM: 64x64 tiles -> 1024 blocks (4/CU TLP) + R16 DOUBLE-BUFFERED
// staging (one barrier/iter; per-iter compute is only 4 MFMA, so the exposed
// DMA drain dominated the single-buffer version).  LDS 16 KB.
__global__ __launch_bounds__(256) void gemm64_kernel(
    const __bf16* __restrict__ A, const __bf16* __restrict__ W,
    const float* __restrict__ bias, int K, float* __restrict__ out, int ldo)
{
  const int tid = threadIdx.x;
  const int lane = tid & 63, wave = tid >> 6;
  const int lr = lane & 15, lq = lane >> 4;
  const int m_blk = blockIdx.y * 64, n_blk = blockIdx.x * 64;
  const int wm = (wave & 1) * 32, wn = (wave >> 1) * 32;

  __shared__ __align__(16) __bf16 As[2][64 * 32];
  __shared__ __align__(16) __bf16 Bs[2][64 * 32];

  const int srow = tid >> 2, scol = (tid & 3) * 8;
  const __bf16* ag = A + (size_t)(m_blk + srow) * K + scol;
  const __bf16* bg = W + (size_t)(n_blk + srow) * K + scol;

  auto stage = [&](int k0, int bsel) {
    gload_lds16(ag + k0, &As[bsel][tid * 8]);
    gload_lds16(bg + k0, &Bs[bsel][tid * 8]);
  };

  f4 acc[2][2] = {};
  const int nk = K >> 5;

  stage(0, 0);
  for (int k = 0; k < nk; ++k) {
    __syncthreads();   // drains DMA(k); readers of buf[k&1] (iter k-2) done
    if (k + 1 < nk) stage((k + 1) * 32, (k + 1) & 1);

    const __bf16* Ab = As[k & 1];
    const __bf16* Bw = Bs[k & 1];
    bf8 af[2], bfr[2];
    #pragma unroll
    for (int i = 0; i < 2; ++i)
      af[i] = *(const bf8*)&Ab[(wm + i * 16 + lr) * 32 + lq * 8];
    #pragma unroll
    for (int j = 0; j < 2; ++j)
      bfr[j] = *(const bf8*)&Bw[(wn + j * 16 + lr) * 32 + lq * 8];
    #pragma unroll
    for (int i = 0; i < 2; ++i)
      #pragma unroll
      for (int j = 0; j < 2; ++j)
        acc[i][j] = __builtin_amdgcn_mfma_f32_16x16x32_bf16(af[i], bfr[j], acc[i][j], 0, 0, 0);
  }

  #pragma unroll
  for (int i = 0; i < 2; ++i)
    #pragma unroll
    for (int j = 0; j < 2; ++j)
      #pragma unroll
      for (int r = 0; r < 4; ++r) {
        int row = m_blk + wm + i * 16 + lq * 4 + r;
        int col = n_blk + wn + j * 16 + lr;
        out[(size_t)row * ldo + col] = acc[i][j][r] + bias[col];
      }
}

// Flash attention with sink, fixed softmax reference m=0, log2-domain scores.
// 1024 blocks x 256 threads (4 waves x 16 q = 64 q/block), K/V double-
// buffered (40 KB LDS -> 4 blocks/CU).  Balanced pairing: qt + qt' = 31.
__global__ __launch_bounds__(256) void attn_kernel(
    const __bf16* __restrict__ q_ws, const __bf16* __restrict__ k_ws,
    const __bf16* __restrict__ v_ws, const float* __restrict__ sink,
    __bf16* __restrict__ y_ws)
{
  int bi = blockIdx.x;
  int qt, bhi;
  if (bi < 512) { qt = 31 - (bi >> 5); bhi = bi & 31; }
  else          { qt = (bi - 512) >> 5; bhi = (bi - 512) & 31; }
  const int h = bhi & (Hh - 1);
  const int b = bhi >> 4;
  const int tid = threadIdx.x;
  const int lane = tid & 63, wave = tid >> 6;          // wave 0..3
  const int lr = lane & 15, lq = lane >> 4;

  __shared__ __align__(16) __bf16 KsU[2][64 * 64];     // swizzled [key][d], dbuf
  __shared__ __align__(16) __bf16 VtU[2][64 * 64];     // swizzled [d][key], dbuf
  __shared__ __align__(16) __bf16 PsU[4][16 * 64];     // per-wave [q][key]

  const __bf16* qp = q_ws + (size_t)bhi * Tt * Dd;
  const __bf16* kp = k_ws + (size_t)bhi * Tt * Dd;
  const __bf16* vp = v_ws + (size_t)bhi * Dd * Tt;     // [d][t]

  const int qbase = qt * 64;
  const int qlo = qbase + wave * 16;                   // wave's lowest q row

  // Q fragments: 16 rows/wave, loop-invariant registers
  bf8 qf[2];
  {
    const __bf16* qrow = qp + (size_t)(qlo + lr) * Dd;
    qf[0] = *(const bf8*)(qrow + lq * 8);
    qf[1] = *(const bf8*)(qrow + 32 + lq * 8);
  }

  float rs = 0.f;             // per-lane denominator partial (q = lr)
  f4 o_acc[4] = {};

  // staging: 256 threads, 2 K chunks + 2 V chunks each (64 rows x 8 slots)
  const int srow_lo = tid >> 3;         // 0..31
  const int sslot = tid & 7;
  const int nkt = qt + 1;

  auto stage = [&](int kt2, int bsel) {
    const int kbase2 = kt2 * 64;
    #pragma unroll
    for (int ii = 0; ii < 2; ++ii) {
      const int r = ii * 32 + srow_lo;
      const int cc = sslot ^ (r & 7);            // XOR granule swizzle
      gload_lds16(kp + (size_t)(kbase2 + r) * Dd + cc * 8,
                  &KsU[bsel][ii * 2048 + tid * 8]);
      gload_lds16(vp + (size_t)r * Tt + kbase2 + cc * 8,
                  &VtU[bsel][ii * 2048 + tid * 8]);
    }
  };

  stage(0, 0);
  for (int kt = 0; kt < nkt; ++kt) {
    __syncthreads();        // drains DMA(kt); readers of buf[kt&1] (iter kt-2) done
    if (kt + 1 < nkt) stage(kt + 1, (kt + 1) & 1);

    const __bf16* Kb = KsU[kt & 1];
    const __bf16* Vb = VtU[kt & 1];
    const int kbase = kt * 64;

    // S^T = K Q^T (A=K rows, B=Q rows): c[r] = S[key=kbase+nt*16+lq*4+r][q=qlo+lr]
    f4 s[4];
    #pragma unroll
    for (int nt = 0; nt < 4; ++nt) {
      const int krow = nt * 16 + lr;
      const int x7 = krow & 7;
      bf8 kb0 = *(const bf8*)&Kb[krow * 64 + ((lq ^ x7) * 8)];
      bf8 kb1 = *(const bf8*)&Kb[krow * 64 + (((4 + lq) ^ x7) * 8)];
      f4 c = {};
      c = __builtin_amdgcn_mfma_f32_16x16x32_bf16(kb0, qf[0], c, 0, 0, 0);
      c = __builtin_amdgcn_mfma_f32_16x16x32_bf16(kb1, qf[1], c, 0, 0, 0);
      s[nt] = c;
    }

    __bf16* Pw = PsU[wave];
    if (kt == qt) {         // diagonal tile (only one per wave at 64-q blocks)
      #pragma unroll
      for (int nt = 0; nt < 4; ++nt) {
        const int qg = qlo + lr;
        const int kg = kbase + nt * 16 + lq * 4;
        bf4 pb;
        #pragma unroll
        for (int r = 0; r < 4; ++r) {
          float sv = (kg + r > qg) ? -1e30f : s[nt][r];
          float p = ex2(sv);              // scores already in log2 domain
          rs += p;
          pb[r] = (__bf16)p;
        }
        const int G = (nt * 2 + (lq >> 1)) ^ (lr & 7);
        *(bf4*)&Pw[lr * 64 + G * 8 + (lq & 1) * 4] = pb;
      }
    } else {
      #pragma unroll
      for (int nt = 0; nt < 4; ++nt) {
        bf4 pb;
        #pragma unroll
        for (int r = 0; r < 4; ++r) {
          float p = ex2(s[nt][r]);
          rs += p;
          pb[r] = (__bf16)p;
        }
        const int G = (nt * 2 + (lq >> 1)) ^ (lr & 7);
        *(bf4*)&Pw[lr * 64 + G * 8 + (lq & 1) * 4] = pb;
      }
    }
    asm volatile("s_waitcnt lgkmcnt(0)" ::: "memory");  // wave-private RAW on Pw

    // O += P @ V
    #pragma unroll
    for (int ks = 0; ks < 2; ++ks) {
      const int pg = ((ks * 4 + lq) ^ (lr & 7)) * 8;
      bf8 pa = *(const bf8*)&Pw[lr * 64 + pg];
      #pragma unroll
      for (int dt = 0; dt < 4; ++dt) {
        const int vrow = dt * 16 + lr;
        bf8 vb = *(const bf8*)&Vb[vrow * 64 + (((ks * 4 + lq) ^ (vrow & 7)) * 8)];
        o_acc[dt] = __builtin_amdgcn_mfma_f32_16x16x32_bf16(pa, vb, o_acc[dt], 0, 0, 0);
      }
    }
  }

  // denominator: reduce per-lane partials over lq (lanes sharing lr)
  rs += __shfl_xor(rs, 16, 64);
  rs += __shfl_xor(rs, 32, 64);
  const float snk = ex2(sink[h] * 1.44269504f);   // e^sink
  float inv = 1.0f / (rs + snk);
  // redistribute: O rows are q = lq*4+r; denom lives at lane with lr == lq*4+r
  float invr[4];
  #pragma unroll
  for (int r = 0; r < 4; ++r)
    invr[r] = __shfl(inv, lq * 4 + r, 64);

  #pragma unroll
  for (int dt = 0; dt < 4; ++dt)
    #pragma unroll
    for (int r = 0; r < 4; ++r) {
      int qrow = qlo + lq * 4 + r;
      y_ws[((size_t)b * Tt + qrow) * Cc + h * Dd + dt * 16 + lr] =
          (__bf16)(o_acc[dt][r] * invr[r]);
    }
}

extern "C" void kernel_launch(void* const* d_in, const int* in_sizes, int n_in,
                              void* d_out, int out_size, void* d_ws, size_t ws_size,
                              hipStream_t stream) {
  const float* x      = (const float*)d_in[0];
  const float* W_qkv  = (const float*)d_in[1];
  const float* b_qkv  = (const float*)d_in[2];
  const float* W_proj = (const float*)d_in[3];
  const float* b_proj = (const float*)d_in[4];
  const float* sinkp  = (const float*)d_in[5];
  float* out = (float*)d_out;

  const size_t n_x    = (size_t)Bb * Tt * Cc;        // 4.19M
  const size_t n_wqkv = (size_t)3 * Hh * Dd * Cc;    // 3.15M
  const size_t n_wprj = (size_t)Cc * Hh * Dd;        // 1.05M
  const size_t nqkv   = (size_t)Bb * Hh * Tt * Dd;   // 4.19M

  __bf16* xb     = (__bf16*)d_ws;          // also aliased as y_ws after QKV GEMM
  __bf16* wqkvb  = xb + n_x;
  __bf16* wprojb = wqkvb + n_wqkv;
  __bf16* q_ws   = wprojb + n_wprj;
  __bf16* k_ws   = q_ws + nqkv;
  __bf16* v_ws   = k_ws + nqkv;
  __bf16* y_ws   = xb;                     // lifetime-disjoint alias

  dim3 blk(256);
  const int cvt_blocks = (int)((n_x + n_wqkv + n_wprj) / 8 / 256);  // 4096
  cvt3_kernel<<<cvt_blocks, blk, 0, stream>>>(x, xb, (int)n_x,
                                              W_qkv, wqkvb, (int)n_wqkv,
                                              W_proj, wprojb);

  // QKV: M=4096, N=3072, K=1024 — 768 blocks (3/CU), dbuf (R14 config)
  gemm128_kernel<<<dim3(3 * Cc / 128, Bb * Tt / 128), blk, 0, stream>>>(
      xb, wqkvb, b_qkv, Cc, q_ws, k_ws, v_ws);
  // attention: 1024 balanced-pair blocks, 256 threads, 4 blocks/CU
  attn_kernel<<<dim3(1024), blk, 0, stream>>>(q_ws, k_ws, v_ws, sinkp, y_ws);
  // proj: M=4096, N=1024, K=1024 — 64x64 tiles -> 1024 blocks (4/CU), dbuf
  gemm64_kernel<<<dim3(Cc / 64, Bb * Tt / 64), blk, 0, stream>>>(
      y_ws, wprojb, b_proj, Hh * Dd, out, Cc);
}